// Round 6
// baseline (418.535 us; speedup 1.0000x reference)
//
#include <hip/hip_runtime.h>
#include <hip/hip_cooperative_groups.h>
#include <stdint.h>

namespace cg = cooperative_groups;

#define HW 4096
#define NC 512
#define NB 8

typedef __attribute__((ext_vector_type(8))) short short8;
typedef __attribute__((ext_vector_type(4))) float f32x4;

__device__ __forceinline__ unsigned short f2bf(float f) {
  unsigned int u = __builtin_bit_cast(unsigned int, f);
  unsigned int r = (u + 0x7FFFu + ((u >> 16) & 1u)) >> 16;
  return (unsigned short)r;
}
__device__ __forceinline__ float hsig(float v) {
  return fminf(fmaxf((v + 3.0f) * (1.0f / 6.0f), 0.0f), 1.0f);
}

// 512-thread block reduce (8 waves)
__device__ __forceinline__ float br_sum(float v, volatile float* red) {
#pragma unroll
  for (int m = 1; m < 64; m <<= 1) v += __shfl_xor(v, m);
  if ((threadIdx.x & 63) == 0) red[threadIdx.x >> 6] = v;
  __syncthreads();
  float r = ((red[0] + red[1]) + (red[2] + red[3])) + ((red[4] + red[5]) + (red[6] + red[7]));
  __syncthreads();
  return r;
}
__device__ __forceinline__ float br_max(float v, volatile float* red) {
#pragma unroll
  for (int m = 1; m < 64; m <<= 1) v = fmaxf(v, __shfl_xor(v, m));
  if ((threadIdx.x & 63) == 0) red[threadIdx.x >> 6] = v;
  __syncthreads();
  float r = fmaxf(fmaxf(fmaxf(red[0], red[1]), fmaxf(red[2], red[3])),
                  fmaxf(fmaxf(red[4], red[5]), fmaxf(red[6], red[7])));
  __syncthreads();
  return r;
}

__device__ __forceinline__ float dot64(const float4* __restrict__ w,
                                       const float4* __restrict__ v) {
  float p0 = 0.f, p1 = 0.f, p2 = 0.f, p3 = 0.f;
#pragma unroll 8
  for (int i = 0; i < 64; i += 4) {
    float4 w0 = w[i], w1 = w[i + 1], w2 = w[i + 2], w3 = w[i + 3];
    float4 a0 = v[i], a1 = v[i + 1], a2 = v[i + 2], a3 = v[i + 3];
    p0 += w0.x * a0.x + w0.y * a0.y + w0.z * a0.z + w0.w * a0.w;
    p1 += w1.x * a1.x + w1.y * a1.y + w1.z * a1.z + w1.w * a1.w;
    p2 += w2.x * a2.x + w2.y * a2.y + w2.z * a2.z + w2.w * a2.w;
    p3 += w3.x * a3.x + w3.y * a3.y + w3.z * a3.z + w3.w * a3.w;
  }
  return (p0 + p1) + (p2 + p3);
}

// ---------- shared phase bodies ----------

// phase-1 unit: one 64c x 64hw tile, executed by a 256-thread group.
// u encodes (hx, cy, b). Also converts res_w row u when u < 512.
template <typename SPL, typename TLL>
__device__ __forceinline__ void p1_unit(
    int u, int tt, SPL sp_l, TLL tl,
    const float* __restrict__ x, const float* __restrict__ w_conv1,
    const float* __restrict__ res_w, float* __restrict__ g_sum,
    float* __restrict__ spat, unsigned short* __restrict__ xTS,
    unsigned short* __restrict__ wbfS) {
  const int cgi = tt >> 4, hg = tt & 15;
  const int hx = u & 63, cy = (u >> 6) & 7, b = u >> 9;
  const int c0 = cy * 64, h0 = hx * 64;
  float vv[4][4], wc[4];
  const float* xb = x + ((size_t)(b * NC + c0 + cgi * 4) * HW) + h0 + hg * 4;
#pragma unroll
  for (int i = 0; i < 4; i++) {
    float4 v = *(const float4*)(xb + (size_t)i * HW);
    vv[i][0] = v.x; vv[i][1] = v.y; vv[i][2] = v.z; vv[i][3] = v.w;
    wc[i] = w_conv1[c0 + cgi * 4 + i];
  }
#pragma unroll
  for (int i = 0; i < 4; i++) {
    float sg = vv[i][0] + vv[i][1] + vv[i][2] + vv[i][3];
    sg += __shfl_xor(sg, 1); sg += __shfl_xor(sg, 2);
    sg += __shfl_xor(sg, 4); sg += __shfl_xor(sg, 8);
    if (hg == 0) atomicAdd(&g_sum[b * NC + c0 + cgi * 4 + i], sg);
  }
  {
    float4 sp;
    sp.x = vv[0][0] * wc[0] + vv[1][0] * wc[1] + vv[2][0] * wc[2] + vv[3][0] * wc[3];
    sp.y = vv[0][1] * wc[0] + vv[1][1] * wc[1] + vv[2][1] * wc[2] + vv[3][1] * wc[3];
    sp.z = vv[0][2] * wc[0] + vv[1][2] * wc[1] + vv[2][2] * wc[2] + vv[3][2] * wc[3];
    sp.w = vv[0][3] * wc[0] + vv[1][3] * wc[1] + vv[2][3] * wc[2] + vv[3][3] * wc[3];
    *(float4*)&sp_l[cgi][hg * 4] = sp;
  }
#pragma unroll
  for (int j = 0; j < 4; j++) {
    ushort4 uu;
    uu.x = f2bf(vv[0][j]); uu.y = f2bf(vv[1][j]);
    uu.z = f2bf(vv[2][j]); uu.w = f2bf(vv[3][j]);
    *(ushort4*)&tl[(hg * 4 + j) * 72 + cgi * 4] = uu;
  }
  __syncthreads();
  if (tt < 64) {
    float sv = 0.f;
#pragma unroll
    for (int i = 0; i < 16; i++) sv += sp_l[i][tt];
    atomicAdd(&spat[b * HW + h0 + tt], sv);
  }
  const int w = tt >> 6, l = tt & 63;
#pragma unroll
  for (int ff = w; ff < 8; ff += 4) {
    const int fr = ff >> 1, fk = ff & 1;
    short8 v = *(const short8*)&tl[(fr * 16 + (l & 15)) * 72 + (fk * 4 + (l >> 4)) * 8];
    size_t tile = (size_t)(b * 256 + (h0 >> 4) + fr) * 16 + (c0 >> 5) + fk;
    *(short8*)(xTS + tile * 512 + l * 8) = v;
  }
  if (u < 512 && tt < 64) {
    const int q = u;
    float4 a = *(const float4*)(res_w + (size_t)q * 512 + tt * 8);
    float4 c2 = *(const float4*)(res_w + (size_t)q * 512 + tt * 8 + 4);
    short8 v;
    v[0] = (short)f2bf(a.x); v[1] = (short)f2bf(a.y);
    v[2] = (short)f2bf(a.z); v[3] = (short)f2bf(a.w);
    v[4] = (short)f2bf(c2.x); v[5] = (short)f2bf(c2.y);
    v[6] = (short)f2bf(c2.z); v[7] = (short)f2bf(c2.w);
    const int lq = (q & 15) + ((tt & 3) << 4);
    *(short8*)(wbfS + ((size_t)(q >> 4) * 16 + (tt >> 2)) * 512 + lq * 8) = v;
  }
  __syncthreads();
}

// phase-2A body: per (b,q) 512-thread block. s/Ssum, mv1, mv2, LN, P, u.
__device__ __forceinline__ void p2a_body(
    int b, int q, int t, float* s_l, float* v512, float* v256, float* red,
    const float* __restrict__ spat, const float* __restrict__ g_sum,
    const float* __restrict__ w_b1, const float* __restrict__ b_b1,
    const float* __restrict__ w_b2, const float* __restrict__ b_b2,
    const float* __restrict__ ln_g, const float* __restrict__ ln_b,
    float* __restrict__ s, float* __restrict__ Ssum, float* __restrict__ t_arr,
    float* __restrict__ P, float* __restrict__ u_) {
  float part = 0.f;
#pragma unroll
  for (int i = 0; i < 8; i++) {
    int j = t + i * 512;
    float sv = hsig(spat[b * HW + j]);
    s_l[j] = sv;
    part += sv;
  }
  float Ss = br_sum(part, red);
  s[b * HW + q * 512 + t] = s_l[q * 512 + t];
  if (q == 0 && t == 0) Ssum[b] = Ss;
  v512[t] = g_sum[b * NC + t] * (1.0f / 4096.0f);
  __syncthreads();
  {
    int o = t >> 1, kq = t & 1;
    float d = dot64((const float4*)(w_b1 + (size_t)o * 512 + kq * 256),
                    (const float4*)(v512 + kq * 256));
    d += __shfl_xor(d, 1);
    if (kq == 0) v256[o] = fmaxf(d + b_b1[o], 0.0f);
  }
  __syncthreads();
  float ca2 = hsig(dot64((const float4*)(w_b2 + (size_t)t * 256),
                         (const float4*)v256) + b_b2[t]);
  float S1 = br_sum(ca2, red);
  float S2 = br_sum(ca2 * ca2, red);
  float mu = S1 * (1.0f / 512.0f);
  float var = S2 * (1.0f / 512.0f) - mu * mu;
  float rstd = rsqrtf(var + 1e-6f);
  float tval = (ca2 - mu) * rstd * ln_g[t] + ln_b[t];
  v512[t] = tval;  // reuse v512 as t_l
  if (q == 0) t_arr[b * NC + t] = tval;
  __syncthreads();
  {
    int c = q * 64 + (t >> 3), r = t & 7;
    float tc = v512[c];
    float sum = 0.f;
#pragma unroll 8
    for (int jj = 0; jj < 512; jj++) {
      int idx = (jj + r * 4) & 511;
      sum += floorf((s_l[r * 512 + idx] + tc) * 0.5f);
    }
    sum += __shfl_xor(sum, 1);
    sum += __shfl_xor(sum, 2);
    sum += __shfl_xor(sum, 4);
    if (r == 0) {
      P[b * NC + c] = sum;
      u_[b * NC + c] = (tc * Ss + sum) * (1.0f / 4096.0f);
    }
  }
}

// phase-2B body: per-b 512-thread block. sk MLP + softmax + coef.
__device__ __forceinline__ void p2b_body(
    int b, int t, float* v512, float* v256, float* red,
    const float* __restrict__ u_, const float* __restrict__ sk_w1,
    const float* __restrict__ sk_w2, const float* __restrict__ t_arr,
    const float* __restrict__ P, const float* __restrict__ Ssum,
    float* __restrict__ coef) {
  const float Ssv = Ssum[b];
  v512[t] = u_[b * NC + t];
  __syncthreads();
  {
    int o = t >> 1, kq = t & 1;
    float d = dot64((const float4*)(sk_w1 + (size_t)o * 512 + kq * 256),
                    (const float4*)(v512 + kq * 256));
    d += __shfl_xor(d, 1);
    if (kq == 0) v256[o] = fmaxf(d, 0.0f);
  }
  __syncthreads();
  float u2 = fmaxf(dot64((const float4*)(sk_w2 + (size_t)t * 256),
                         (const float4*)v256), 0.0f);
  float M = br_max(u2, red);
  float e = __expf(u2 - M);
  float Z = br_sum(e, red);
  float a = e / Z;
  float tc = t_arr[b * NC + t];
  float Pv = P[b * NC + t];
  float4 cf = {a * tc, 1.0f - a, a * tc * Ssv + (1.0f - a) * Pv, tc};
  *(float4*)(coef + (size_t)(b * NC + t) * 4) = cf;
}

// phase-3 body: one (nb, b3) tile = full M=512 x N=64, 8 waves, LDS-free.
__device__ __forceinline__ void p3_tile(
    int nb, int b3, int t,
    const unsigned short* __restrict__ wbfS, const unsigned short* __restrict__ xTS,
    const float* __restrict__ x, const float* __restrict__ s,
    const float* __restrict__ coef, float* __restrict__ out) {
  const int w = t >> 6, l = t & 63;
  const int l16 = l & 15, quad = l >> 4;
  f32x4 acc[4][4];
#pragma unroll
  for (int mi = 0; mi < 4; mi++)
#pragma unroll
    for (int ni = 0; ni < 4; ni++) {
      f32x4 z = {0.f, 0.f, 0.f, 0.f};
      acc[mi][ni] = z;
    }
  const unsigned short* Ab = wbfS + (size_t)(w * 4) * 16 * 512 + l * 8;
  const unsigned short* Bb = xTS + (size_t)(b3 * 256 + nb * 4) * 16 * 512 + l * 8;
#pragma unroll 2
  for (int kk = 0; kk < 16; kk++) {
    short8 af[4], bfr[4];
#pragma unroll
    for (int mi = 0; mi < 4; mi++)
      af[mi] = *(const short8*)(Ab + ((size_t)mi * 16 + kk) * 512);
#pragma unroll
    for (int ni = 0; ni < 4; ni++)
      bfr[ni] = *(const short8*)(Bb + ((size_t)ni * 16 + kk) * 512);
#pragma unroll
    for (int mi = 0; mi < 4; mi++)
#pragma unroll
      for (int ni = 0; ni < 4; ni++)
        acc[mi][ni] = __builtin_amdgcn_mfma_f32_16x16x32_bf16(af[mi], bfr[ni], acc[mi][ni], 0, 0, 0);
  }
  const int n0 = nb * 64;
  float sv[4];
#pragma unroll
  for (int ni = 0; ni < 4; ni++) sv[ni] = s[b3 * HW + n0 + ni * 16 + l16];
#pragma unroll
  for (int mi = 0; mi < 4; mi++) {
#pragma unroll
    for (int r = 0; r < 4; r++) {
      const int o = w * 64 + mi * 16 + quad * 4 + r;
      float4 cf = *(const float4*)(coef + (size_t)(b3 * NC + o) * 4);
      const size_t row = (size_t)(b3 * NC + o) * HW + n0;
#pragma unroll
      for (int ni = 0; ni < 4; ni++) {
        const int nn = ni * 16 + l16;
        float sel = cf.x * sv[ni] + cf.y * floorf((sv[ni] + cf.w) * 0.5f);
        out[row + nn] = x[row + nn] * sel + cf.z + acc[mi][ni][r];
      }
    }
  }
}

// ---------- workspace layout ----------
#define WS_PTRS(ws)                                              \
  float* g_sum = (float*)(ws);                                   \
  float* spat  = (float*)(ws + 0x08000);                         \
  float* Ssum  = (float*)(ws + 0x28000);                         \
  float* P     = (float*)(ws + 0x30000);                         \
  float* coef  = (float*)(ws + 0x38000);                         \
  float* s     = (float*)(ws + 0x50000);                         \
  float* u_    = (float*)(ws + 0x78000);                         \
  float* t_arr = (float*)(ws + 0x7C000);                         \
  unsigned short* wbfS = (unsigned short*)(ws + 0x80000);        \
  unsigned short* xTS  = (unsigned short*)(ws + 0x100000);

struct SP1 { float sp[2][16][64]; unsigned short tl[2][64 * 72]; };
struct SP2 { float s_l[HW]; float v512[NC]; float v256[256]; float red[8]; };
union SMem { SP1 p1; SP2 p2; };

// ---------- cooperative mega-kernel (grid 256 x 512) ----------
__global__ __launch_bounds__(512, 4) void mega(
    const float* __restrict__ x, const float* __restrict__ w_b1,
    const float* __restrict__ b_b1, const float* __restrict__ w_b2,
    const float* __restrict__ b_b2, const float* __restrict__ w_conv1,
    const float* __restrict__ ln_g, const float* __restrict__ ln_b,
    const float* __restrict__ sk_w1, const float* __restrict__ sk_w2,
    const float* __restrict__ res_w, char* __restrict__ ws,
    float* __restrict__ out) {
  __shared__ SMem sm;
  cg::grid_group gridg = cg::this_grid();
  const int t = threadIdx.x;
  const int bx = blockIdx.x;
  WS_PTRS(ws)

  // phase 0: zero g_sum + spat (0x28000 bytes = 40960 floats)
  { int i = bx * 512 + t; if (i < 40960) ((float*)ws)[i] = 0.f; }
  gridg.sync();

  // phase 1: 4096 units over 256 blocks x 2 sub-blocks x 8 iters
  {
    const int sb = t >> 8, tt = t & 255;
    for (int it = 0; it < 8; it++) {
      const int u = bx * 16 + sb * 8 + it;
      p1_unit(u, tt, sm.p1.sp[sb], sm.p1.tl[sb], x, w_conv1, res_w,
              g_sum, spat, xTS, wbfS);
    }
  }
  gridg.sync();

  // phase 2A (64 blocks)
  if (bx < 64)
    p2a_body(bx >> 3, bx & 7, t, sm.p2.s_l, sm.p2.v512, sm.p2.v256, sm.p2.red,
             spat, g_sum, w_b1, b_b1, w_b2, b_b2, ln_g, ln_b,
             s, Ssum, t_arr, P, u_);
  gridg.sync();

  // phase 2B (8 blocks)
  if (bx < 64 && (bx & 7) == 0)
    p2b_body(bx >> 3, t, sm.p2.v512, sm.p2.v256, sm.p2.red,
             u_, sk_w1, sk_w2, t_arr, P, Ssum, coef);
  gridg.sync();

  // phase 3: 512 tiles over 256 blocks x 2
#pragma unroll
  for (int j = 0; j < 2; j++) {
    const int id = bx * 2 + j;
    p3_tile(id & 63, id >> 6, t, wbfS, xTS, x, s, coef, out);
  }
}

// ---------- fallback kernels (separate launches) ----------
__global__ __launch_bounds__(256) void k1f(
    const float* __restrict__ x, const float* __restrict__ w_conv1,
    const float* __restrict__ res_w, char* __restrict__ ws) {
  __shared__ float sp_l[16][64];
  __shared__ unsigned short tl[64 * 72];
  WS_PTRS(ws)
  (void)Ssum; (void)P; (void)coef; (void)s; (void)u_; (void)t_arr;
  const int u = (blockIdx.z << 9) + (blockIdx.y << 6) + blockIdx.x;
  p1_unit(u, (int)threadIdx.x, sp_l, tl, x, w_conv1, res_w, g_sum, spat, xTS, wbfS);
}

__global__ __launch_bounds__(512) void k2af(
    const float* __restrict__ w_b1, const float* __restrict__ b_b1,
    const float* __restrict__ w_b2, const float* __restrict__ b_b2,
    const float* __restrict__ ln_g, const float* __restrict__ ln_b,
    char* __restrict__ ws) {
  __shared__ SP2 sm2;
  WS_PTRS(ws)
  (void)coef; (void)wbfS; (void)xTS;
  p2a_body(blockIdx.x >> 3, blockIdx.x & 7, (int)threadIdx.x,
           sm2.s_l, sm2.v512, sm2.v256, sm2.red,
           spat, g_sum, w_b1, b_b1, w_b2, b_b2, ln_g, ln_b,
           s, Ssum, t_arr, P, u_);
}

__global__ __launch_bounds__(512) void k2bf(
    const float* __restrict__ sk_w1, const float* __restrict__ sk_w2,
    char* __restrict__ ws) {
  __shared__ float v512[NC];
  __shared__ float v256[256];
  __shared__ float red[8];
  WS_PTRS(ws)
  (void)g_sum; (void)spat; (void)s; (void)wbfS; (void)xTS;
  p2b_body(blockIdx.x, (int)threadIdx.x, v512, v256, red,
           u_, sk_w1, sk_w2, t_arr, P, Ssum, coef);
}

__global__ __launch_bounds__(512, 4) void k3f(
    const float* __restrict__ x, char* __restrict__ ws, float* __restrict__ out) {
  WS_PTRS(ws)
  (void)g_sum; (void)spat; (void)Ssum; (void)P; (void)u_; (void)t_arr;
  p3_tile(blockIdx.x, blockIdx.y, (int)threadIdx.x, wbfS, xTS, x, s, coef, out);
}

extern "C" void kernel_launch(void* const* d_in, const int* in_sizes, int n_in,
                              void* d_out, int out_size, void* d_ws, size_t ws_size,
                              hipStream_t stream) {
  const float* x       = (const float*)d_in[0];
  const float* w_b1    = (const float*)d_in[1];
  const float* b_b1    = (const float*)d_in[2];
  const float* w_b2    = (const float*)d_in[3];
  const float* b_b2    = (const float*)d_in[4];
  const float* w_conv1 = (const float*)d_in[5];
  const float* ln_g    = (const float*)d_in[6];
  const float* ln_b    = (const float*)d_in[7];
  const float* sk_w1   = (const float*)d_in[8];
  const float* sk_w2   = (const float*)d_in[9];
  const float* res_w   = (const float*)d_in[10];
  float* out = (float*)d_out;
  char* ws = (char*)d_ws;

  void* args[] = {(void*)&x, (void*)&w_b1, (void*)&b_b1, (void*)&w_b2, (void*)&b_b2,
                  (void*)&w_conv1, (void*)&ln_g, (void*)&ln_b, (void*)&sk_w1,
                  (void*)&sk_w2, (void*)&res_w, (void*)&ws, (void*)&out};
  hipError_t err = hipLaunchCooperativeKernel(mega, dim3(256), dim3(512), args, 0, stream);
  if (err != hipSuccess) {
    // fallback: proven multi-kernel path
    hipMemsetAsync(ws, 0, 0x28000, stream);
    k1f<<<dim3(64, 8, 8), 256, 0, stream>>>(x, w_conv1, res_w, ws);
    k2af<<<64, 512, 0, stream>>>(w_b1, b_b1, w_b2, b_b2, ln_g, ln_b, ws);
    k2bf<<<8, 512, 0, stream>>>(sk_w1, sk_w2, ws);
    k3f<<<dim3(64, 8), 512, 0, stream>>>(x, ws, out);
  }
}